// Round 26
// baseline (155.614 us; speedup 1.0000x reference)
//
#include <hip/hip_runtime.h>
#include <hip/hip_bf16.h>

#define N_NODES 50000
#define IN_CH 128
#define HID 128
#define OUT_CH 64
#define N_EDGES 800000
#define N_TOT_EDGES (N_EDGES + N_NODES)         // + self loops
#define ET_PAD (N_TOT_EDGES + 3 * N_NODES)      // worst-case pad-to-4 per node
#define MPAD 50048                              // 782 * 64 (gemm row-block pad)
#define NBN ((N_NODES + 255) / 256)             // 196
#define NB_ET ((N_TOT_EDGES + 255) / 256)       // 3321
#define NB_GEMM (MPAD / 64)                     // 782
#define NSH 128                                 // histogram shards
#define EPS (N_EDGES / NSH)                     // 6250 edges per shard
#define NDW (N_NODES / 4)                       // 12500 packed-u8 dwords

typedef float float4v __attribute__((ext_vector_type(4)));
typedef unsigned uint4v __attribute__((ext_vector_type(4)));
typedef __attribute__((ext_vector_type(8))) short bf16x8;
typedef __attribute__((ext_vector_type(4))) float f32x4;

__device__ __forceinline__ unsigned bf16_rne(float f) {
    unsigned u = __float_as_uint(f);
    return (u + 0x7fffu + ((u >> 16) & 1u)) >> 16;
}
__device__ __forceinline__ unsigned pack2(float a, float b) {
    return bf16_rne(a) | (bf16_rne(b) << 16);
}

// ---------------- D0: W1 -> bf16 tiled (r25 post-mortem: inline f32 W in
// gemm1 cost 256 scalar loads/thread, +10us; pre-convert restored) ----------
__global__ __launch_bounds__(256) void k_pre(
        const float* __restrict__ W1, unsigned short* __restrict__ Wl1) {
    const int tg = blockIdx.x * 256 + threadIdx.x;
    if (tg >= 16 * 128) return;
    const int kg = tg >> 7, col = tg & 127;
    float v[8];
    #pragma unroll
    for (int j = 0; j < 8; ++j) v[j] = W1[(size_t)(kg * 8 + j) * 128 + col];
    uint4 p;
    p.x = pack2(v[0], v[1]); p.y = pack2(v[2], v[3]);
    p.z = pack2(v[4], v[5]); p.w = pack2(v[6], v[7]);
    *(uint4*)&Wl1[(size_t)tg * 8] = p;
}

// ---------------- MFMA GEMM body ----------------
// Block = 4 waves; wave = 16 rows x ALL N cols; C/D layout verified (m89/m91).
// AF32: A-frags inline from f32 X. USELDS: stage bf16 W in LDS (else global).
template<int N, bool AF32, bool USELDS>
__device__ __forceinline__ void gemm_body(int gb, int t,
        const float* __restrict__ Xf, const unsigned short* __restrict__ Xb,
        const unsigned short* __restrict__ Wlg,
        const float* __restrict__ asrc, const float* __restrict__ adst,
        unsigned short* __restrict__ Hb, float* __restrict__ als,
        float* __restrict__ ald, int M, unsigned short* Wl) {
    constexpr int NF = N / 16;
    const unsigned short* Wsrc;
    if constexpr (USELDS) {
        for (int i = t; i < N * 16; i += 256)
            ((uint4*)Wl)[i] = ((const uint4*)Wlg)[i];
        __syncthreads();
        Wsrc = Wl;
    } else {
        Wsrc = Wlg;
    }

    const int lane = t & 63, w = t >> 6;
    const int rb = gb * 64 + w * 16;
    const int cl = lane & 15, g = lane >> 4;

    f32x4 acc[NF];
    #pragma unroll
    for (int n = 0; n < NF; ++n) acc[n] = (f32x4){0.f, 0.f, 0.f, 0.f};

    const float* Xrow = nullptr;
    const unsigned short* Abase = nullptr;
    if constexpr (AF32) {
        const int arow = (rb + cl < M) ? (rb + cl) : (M - 1);
        Xrow = Xf + (size_t)arow * 128;
    } else {
        Abase = Xb + (size_t)(rb >> 4) * 2048 + cl * 8;
    }

    #pragma unroll
    for (int s = 0; s < 4; ++s) {
        bf16x8 af;
        if constexpr (AF32) {
            const int k0 = (s * 4 + g) * 8;
            float4 a = *(const float4*)&Xrow[k0];
            float4 c = *(const float4*)&Xrow[k0 + 4];
            uint4v uu;
            uu[0] = pack2(a.x, a.y); uu[1] = pack2(a.z, a.w);
            uu[2] = pack2(c.x, c.y); uu[3] = pack2(c.z, c.w);
            af = __builtin_bit_cast(bf16x8, uu);
        } else {
            af = *(const bf16x8*)(Abase + (s * 4 + g) * 128);
        }
        #pragma unroll
        for (int n = 0; n < NF; ++n) {
            bf16x8 bfv = *(const bf16x8*)(Wsrc + ((s * 4 + g) * N + n * 16 + cl) * 8);
            acc[n] = __builtin_amdgcn_mfma_f32_16x16x32_bf16(af, bfv, acc[n], 0, 0, 0);
        }
    }

    float asv[NF], adv[NF];
    #pragma unroll
    for (int n = 0; n < NF; ++n) {
        asv[n] = asrc[n * 16 + cl];
        adv[n] = adst[n * 16 + cl];
    }

    #pragma unroll
    for (int r = 0; r < 4; ++r) {
        float ps = 0.f, pd = 0.f;
        #pragma unroll
        for (int n = 0; n < NF; ++n) {
            ps += acc[n][r] * asv[n];
            pd += acc[n][r] * adv[n];
        }
        #pragma unroll
        for (int mask = 1; mask < 16; mask <<= 1) {
            ps += __shfl_xor(ps, mask);
            pd += __shfl_xor(pd, mask);
        }
        const int row = rb + g * 4 + r;
        if (cl == 0 && row < M) { als[row] = ps; ald[row] = pd; }
    }

    #pragma unroll
    for (int r = 0; r < 4; ++r) {
        const int row = rb + g * 4 + r;
        if (row >= M) continue;
        #pragma unroll
        for (int n = 0; n < NF; ++n)
            Hb[(size_t)(n >> 1) * (size_t)M * 32 + (size_t)row * 32
               + (n & 1) * 16 + cl] = (unsigned short)bf16_rne(acc[n][r]);
    }
}

// ---------------- D1: [LDS-histogram count || gemm1] ----------------
__global__ __launch_bounds__(256) void k_par1(
        const int* __restrict__ ei, unsigned* __restrict__ cnt_s,
        unsigned char* __restrict__ rank8,
        const float* __restrict__ X, const unsigned short* __restrict__ Wl1,
        const float* __restrict__ asrc, const float* __restrict__ adst,
        unsigned short* __restrict__ Hb, float* __restrict__ als,
        float* __restrict__ ald, int* __restrict__ ticket, int M) {
    __shared__ unsigned lcnt[NDW];               // 50 KB
    const int b = blockIdx.x, t = threadIdx.x;
    if (b == 0 && t == 0) *ticket = 0;           // re-armed every replay
    if (b < NSH) {
        const int s = b;
        for (int i = t; i < NDW; i += 256) lcnt[i] = 0;
        __syncthreads();
        const int base = s * EPS;
        const int* __restrict__ dst = ei + N_EDGES;
        for (int j = base + t; j < base + EPS; j += 256) {
            int d = __builtin_nontemporal_load(&dst[j]);
            unsigned sh = 8u * (d & 3);
            unsigned old = atomicAdd(&lcnt[d >> 2], 1u << sh);
            rank8[j] = (unsigned char)((old >> sh) & 0xFFu);
        }
        __syncthreads();
        unsigned* __restrict__ outp = cnt_s + (size_t)s * NDW;
        for (int i = t; i < NDW; i += 256) outp[i] = lcnt[i];
        return;
    }
    gemm_body<HID, true, false>(b - NSH, t, X, nullptr, Wl1,
                                asrc, adst, Hb, als, ald, M, nullptr);
}

// ---------------- D2: [scan1 + last-block P2 || W2 convert] ----------------
// scan1: fold 128 shard counts -> cntT, u8 per-shard bases, LOCAL padded scan
// (off stays block-local; consumers add P2[(j-1)>>8]). The LAST block to
// finish (device-scope ticket + fences, no dispatch-order assumption) scans
// the 196 block totals and writes the tiny exclusive-prefix table P2.
__global__ void k_scan1(const unsigned* __restrict__ cnt_s, int* __restrict__ cntT,
                        unsigned char* __restrict__ pcoff8,
                        int* __restrict__ off, int* __restrict__ bsum,
                        int* __restrict__ ticket, int* __restrict__ P2,
                        const float* __restrict__ W2, unsigned short* __restrict__ Wl2,
                        int n) {
    __shared__ int s[256];
    __shared__ int isLast;
    const int b = blockIdx.x, t = threadIdx.x;
    if (b >= NBN) {                              // W2 conversion role
        const int tg = (b - NBN) * 256 + t;
        if (tg >= 16 * 64) return;
        const int kg = tg >> 6, col = tg & 63;
        float v[8];
        #pragma unroll
        for (int j = 0; j < 8; ++j) v[j] = W2[(size_t)(kg * 8 + j) * 64 + col];
        uint4 p;
        p.x = pack2(v[0], v[1]); p.y = pack2(v[2], v[3]);
        p.z = pack2(v[4], v[5]); p.w = pack2(v[6], v[7]);
        *(uint4*)&Wl2[(size_t)tg * 8] = p;
        return;
    }
    int i = b * 256 + t;
    int padded = 0;
    if (i < n) {
        const int dw = i >> 2;
        const unsigned sh = 8u * (i & 3);
        int pc = 1;                        // slot 0 = self-loop
        for (int c = 0; c < NSH; ++c) {
            pcoff8[(size_t)c * n + i] = (unsigned char)pc;
            pc += (int)((cnt_s[(size_t)c * NDW + dw] >> sh) & 0xFFu);
        }
        cntT[i] = pc;                      // true degree (incl. self-loop)
        padded = (pc + 3) & ~3;            // pad segments to 4
    }
    s[t] = padded;
    __syncthreads();
    for (int d = 1; d < 256; d <<= 1) {
        int x = (t >= d) ? s[t - d] : 0;
        __syncthreads();
        s[t] += x;
        __syncthreads();
    }
    if (i < n) off[i + 1] = s[t];          // block-LOCAL inclusive scan
    if (i == 0) off[0] = 0;
    if (t == 255) bsum[b] = s[255];
    __threadfence();                       // publish bsum (device scope)
    if (t == 0) isLast = (atomicAdd(ticket, 1) == NBN - 1);
    __syncthreads();
    if (!isLast) return;
    __threadfence();                       // acquire other blocks' bsum
    int v = (t < NBN) ? bsum[t] : 0;
    s[t] = v;
    __syncthreads();
    for (int d = 1; d < 256; d <<= 1) {
        int x = (t >= d) ? s[t - d] : 0;
        __syncthreads();
        s[t] += x;
        __syncthreads();
    }
    if (t < NBN) P2[t] = s[t] - v;         // exclusive prefix of block totals
}

__device__ __forceinline__ int off_base(const int* __restrict__ P2, int j) {
    return (j > 0) ? P2[(j - 1) >> 8] : 0; // OFF[j] = off[j] + off_base(j)
}

// ---------------- D3: fill WITH fused layer-1 edge weights (no csr) ----------
__global__ void k_fillw(const int* __restrict__ ei, const int* __restrict__ off,
                        const int* __restrict__ P2,
                        const unsigned char* __restrict__ rank8,
                        const unsigned char* __restrict__ pcoff8,
                        const float* __restrict__ als, const float* __restrict__ ald,
                        unsigned* __restrict__ ew, int e, int n) {
    int i = blockIdx.x * 256 + threadIdx.x;
    if (i < e) {
        int src = __builtin_nontemporal_load(&ei[i]);
        int dst = __builtin_nontemporal_load(&ei[e + i]);
        int c = i / EPS;
        int pos = off[dst] + off_base(P2, dst)
                + (int)pcoff8[(size_t)c * n + dst] + (int)rank8[i];
        float ev = als[src] + ald[dst];
        ev = ev > 0.f ? ev : 0.2f * ev;
        ew[pos] = ((unsigned)src << 16) | bf16_rne(__expf(ev));
    } else if (i < e + n) {
        int v = i - e;
        float ev = als[v] + ald[v];
        ev = ev > 0.f ? ev : 0.2f * ev;
        ew[off[v] + off_base(P2, v)] = ((unsigned)v << 16) | bf16_rne(__expf(ev));
    }
}

// ---------------- D5: layer-2 GEMM (A from Xb2-tiled bf16; LDS W) -------------
__global__ __launch_bounds__(256) void gemm_mfma64(
        const unsigned short* __restrict__ Xb, const unsigned short* __restrict__ Wlg,
        const float* __restrict__ asrc, const float* __restrict__ adst,
        unsigned short* __restrict__ Hb, float* __restrict__ als,
        float* __restrict__ ald, int M) {
    __shared__ unsigned short Wl[16 * 64 * 8];    // 16 KB
    gemm_body<OUT_CH, false, true>(blockIdx.x, threadIdx.x, nullptr, Xb, Wlg,
                                   asrc, adst, Hb, als, ald, M, Wl);
}

// ---------------- unified SpMM with inline softmax denominator ----------------
// Wave = 16 nodes; 4-lane sub owns one node; lane = 8 bf16 feats. Each lane
// accumulates the full denominator locally (broadcast quads); pads masked via
// slot < rend. INLINEW (layer 2): w recomputed from ew's src field.
template<int F, bool RELU, bool PACKOUT, bool INLINEW>
__global__ __launch_bounds__(256) void k_spmm_b(
        const unsigned short* __restrict__ Hb, const unsigned* __restrict__ ew,
        const float* __restrict__ als, const float* __restrict__ ald,
        const float* __restrict__ bias, const int* __restrict__ off,
        const int* __restrict__ P2, const int* __restrict__ cntT,
        void* __restrict__ outv, int n) {
    constexpr int NCH = F / 32;
    const int chunk = blockIdx.x % NCH;
    const int v = (blockIdx.x / NCH) * 64 + (threadIdx.x >> 2);
    if (v >= n) return;
    const int q = threadIdx.x & 3;                // 8-feat group 0..3
    const int start = off[v] + off_base(P2, v);
    const int pend  = off[v + 1] + P2[v >> 8];    // off_base(P2, v+1)
    const int rend  = start + cntT[v];            // real end (mask bound)
    const float aldv = INLINEW ? ald[v] : 0.f;
    const unsigned short* __restrict__ Hch = Hb + (size_t)chunk * (size_t)n * 32 + q * 8;

    float a0[8] = {}, a1[8] = {}, a2[8] = {}, a3[8] = {};
    float denom = 0.f;

    #define GATB(E, A, IDX)                                              \
        {                                                                \
            float w_;                                                    \
            if (INLINEW) {                                               \
                int s_ = (int)((E) >> 16);                               \
                float e_ = als[s_] + aldv;                               \
                e_ = e_ > 0.f ? e_ : 0.2f * e_;                          \
                w_ = __expf(e_);                                         \
            } else {                                                     \
                w_ = __uint_as_float((E) << 16);                         \
            }                                                            \
            w_ = ((IDX) < rend) ? w_ : 0.f;                              \
            denom += w_;                                                 \
            uint4 h_ = *(const uint4*)&Hch[(size_t)((E) >> 16) * 32];    \
            A[0] += w_ * __uint_as_float(h_.x << 16);                    \
            A[1] += w_ * __uint_as_float(h_.x & 0xffff0000u);            \
            A[2] += w_ * __uint_as_float(h_.y << 16);                    \
            A[3] += w_ * __uint_as_float(h_.y & 0xffff0000u);            \
            A[4] += w_ * __uint_as_float(h_.z << 16);                    \
            A[5] += w_ * __uint_as_float(h_.z & 0xffff0000u);            \
            A[6] += w_ * __uint_as_float(h_.w << 16);                    \
            A[7] += w_ * __uint_as_float(h_.w & 0xffff0000u);            \
        }
    #define GATB4(Q, J) GATB((Q).x, a0, (J)) GATB((Q).y, a1, (J)+1) \
                        GATB((Q).z, a2, (J)+2) GATB((Q).w, a3, (J)+3)

    int j = start;
    for (; j + 4 < pend; j += 8) {
        uint4 eA = *(const uint4*)&ew[j];
        uint4 eB = *(const uint4*)&ew[j + 4];
        GATB4(eA, j)
        GATB4(eB, j + 4)
    }
    if (j < pend) {
        uint4 eA = *(const uint4*)&ew[j];
        GATB4(eA, j)
    }
    #undef GATB4
    #undef GATB

    const float inv = 1.f / (denom + 1e-16f);
    const float* __restrict__ bp = bias + chunk * 32 + q * 8;
    float s[8];
    #pragma unroll
    for (int i = 0; i < 8; ++i) {
        s[i] = (a0[i] + a1[i] + a2[i] + a3[i]) * inv + bp[i];
        if (RELU) s[i] = fmaxf(s[i], 0.f);
    }

    if (PACKOUT) {
        unsigned short* Xb2 = (unsigned short*)outv;
        const int kg = chunk * 4 + q;
        uint4v p;
        p[0] = pack2(s[0], s[1]); p[1] = pack2(s[2], s[3]);
        p[2] = pack2(s[4], s[5]); p[3] = pack2(s[6], s[7]);
        __builtin_nontemporal_store(p,
            (uint4v*)&Xb2[(size_t)(v >> 4) * 2048 + kg * 128 + (v & 15) * 8]);
    } else {
        float* out = (float*)outv;
        float4v o0, o1;
        o0[0] = s[0]; o0[1] = s[1]; o0[2] = s[2]; o0[3] = s[3];
        o1[0] = s[4]; o1[1] = s[5]; o1[2] = s[6]; o1[3] = s[7];
        float* op = out + (size_t)v * F + chunk * 32 + q * 8;
        __builtin_nontemporal_store(o0, (float4v*)op);
        __builtin_nontemporal_store(o1, (float4v*)(op + 4));
    }
}

// ---------------- launch ----------------

extern "C" void kernel_launch(void* const* d_in, const int* in_sizes, int n_in,
                              void* d_out, int out_size, void* d_ws, size_t ws_size,
                              hipStream_t stream) {
    const float* x     = (const float*)d_in[0];
    const int*   ei    = (const int*)d_in[1];
    const float* W1    = (const float*)d_in[2];
    const float* as1   = (const float*)d_in[3];
    const float* ad1   = (const float*)d_in[4];
    const float* b1    = (const float*)d_in[5];
    const float* W2    = (const float*)d_in[6];
    const float* as2   = (const float*)d_in[7];
    const float* ad2   = (const float*)d_in[8];
    const float* b2    = (const float*)d_in[9];
    float* out = (float*)d_out;

    const int Nn = N_NODES;

    // workspace carve-up (256B aligned)
    char* ws = (char*)d_ws;
    size_t o = 0;
    auto carve = [&](size_t bytes) { char* p = ws + o; o = (o + bytes + 255) & ~(size_t)255; return p; };
    int*            off   = (int*)carve((Nn + 1) * sizeof(int));
    int*            cntT  = (int*)carve(Nn * sizeof(int));
    int*            bsum  = (int*)carve(256 * sizeof(int));
    int*            ticket= (int*)carve(256);
    int*            P2    = (int*)carve(256 * sizeof(int));
    unsigned char*  rank8 = (unsigned char*)carve((size_t)N_EDGES);
    unsigned*       cnt_s = (unsigned*)carve((size_t)NSH * NDW * sizeof(unsigned));
    unsigned char*  pcoff8= (unsigned char*)carve((size_t)NSH * Nn);
    unsigned*       ew    = (unsigned*)carve((size_t)ET_PAD * sizeof(unsigned));
    unsigned short* h1b   = (unsigned short*)carve((size_t)Nn * HID * sizeof(unsigned short));
    unsigned short* h2b   = (unsigned short*)carve((size_t)Nn * OUT_CH * sizeof(unsigned short));
    unsigned short* Xb2   = (unsigned short*)carve((size_t)MPAD * 128 * sizeof(unsigned short));
    unsigned short* Wl1   = (unsigned short*)carve(16 * 128 * 8 * sizeof(unsigned short));
    unsigned short* Wl2   = (unsigned short*)carve(16 * 64 * 8 * sizeof(unsigned short));
    float*          als1v = (float*)carve(Nn * sizeof(float));
    float*          ald1v = (float*)carve(Nn * sizeof(float));
    float*          als2v = (float*)carve(Nn * sizeof(float));
    float*          ald2v = (float*)carve(Nn * sizeof(float));

    // D0: W1 pre-convert (8 blocks; r25 rollback)
    k_pre<<<8, 256, 0, stream>>>(W1, Wl1);

    // D1: [LDS-hist count || gemm1 (f32 X inline, bf16 W1 from global)]
    k_par1<<<NSH + NB_GEMM, 256, 0, stream>>>(
        ei, cnt_s, rank8, x, Wl1, as1, ad1, h1b, als1v, ald1v, ticket, Nn);

    // D2: [scan1 + last-block P2 || W2 convert]
    k_scan1<<<NBN + 4, 256, 0, stream>>>(
        cnt_s, cntT, pcoff8, off, bsum, ticket, P2, W2, Wl2, Nn);

    // D3: fill + fused layer-1 edge weights
    k_fillw<<<NB_ET, 256, 0, stream>>>(ei, off, P2, rank8, pcoff8,
                                       als1v, ald1v, ew, N_EDGES, Nn);

    const int nbN64 = (Nn + 63) / 64;

    // D4: layer-1 SpMM (inline denom; y1 in Xb-tiled bf16 layout)
    k_spmm_b<HID, true, true, false><<<nbN64 * (HID / 32), 256, 0, stream>>>(
        h1b, ew, nullptr, nullptr, b1, off, P2, cntT, Xb2, Nn);

    // D5: layer-2 GEMM
    gemm_mfma64<<<NB_GEMM, 256, 0, stream>>>(
        Xb2, Wl2, as2, ad2, h2b, als2v, ald2v, Nn);

    // D6: layer-2 SpMM (inline w from src field + inline denom)
    k_spmm_b<OUT_CH, false, false, true><<<nbN64 * (OUT_CH / 32), 256, 0, stream>>>(
        h2b, ew, als2v, ald2v, b2, off, P2, cntT, out, Nn);
}

// Round 27
// 142.068 us; speedup vs baseline: 1.0954x; 1.0954x over previous
//
#include <hip/hip_runtime.h>
#include <hip/hip_bf16.h>

#define N_NODES 50000
#define IN_CH 128
#define HID 128
#define OUT_CH 64
#define N_EDGES 800000
#define N_TOT_EDGES (N_EDGES + N_NODES)         // + self loops
#define ET_PAD (N_TOT_EDGES + 3 * N_NODES)      // worst-case pad-to-4 per node
#define MPAD 50048                              // 782 * 64 (gemm row-block pad)
#define NBN ((N_NODES + 255) / 256)             // 196
#define NB_ET ((N_TOT_EDGES + 255) / 256)       // 3321
#define NB_GEMM (MPAD / 64)                     // 782
#define NSH 128                                 // histogram shards
#define EPS (N_EDGES / NSH)                     // 6250 edges per shard
#define NDW (N_NODES / 4)                       // 12500 packed-u8 dwords

typedef float float4v __attribute__((ext_vector_type(4)));
typedef unsigned uint4v __attribute__((ext_vector_type(4)));
typedef __attribute__((ext_vector_type(8))) short bf16x8;
typedef __attribute__((ext_vector_type(4))) float f32x4;

__device__ __forceinline__ unsigned bf16_rne(float f) {
    unsigned u = __float_as_uint(f);
    return (u + 0x7fffu + ((u >> 16) & 1u)) >> 16;
}
__device__ __forceinline__ unsigned pack2(float a, float b) {
    return bf16_rne(a) | (bf16_rne(b) << 16);
}

// ---------------- D1: W1/W2 -> bf16 tiled ----------------
__global__ __launch_bounds__(256) void k_pre(
        const float* __restrict__ W1, unsigned short* __restrict__ Wl1,
        const float* __restrict__ W2, unsigned short* __restrict__ Wl2) {
    const int b = blockIdx.x, t = threadIdx.x;
    const float* W; unsigned short* Wl; int N, bb;
    if (b < 8) { W = W1; Wl = Wl1; N = 128; bb = b; }
    else       { W = W2; Wl = Wl2; N = 64;  bb = b - 8; }
    const int tg = bb * 256 + t;
    if (tg >= 16 * N) return;
    const int kg = tg / N, col = tg & (N - 1);
    float v[8];
    #pragma unroll
    for (int j = 0; j < 8; ++j) v[j] = W[(size_t)(kg * 8 + j) * N + col];
    uint4 p;
    p.x = pack2(v[0], v[1]); p.y = pack2(v[2], v[3]);
    p.z = pack2(v[4], v[5]); p.w = pack2(v[6], v[7]);
    *(uint4*)&Wl[(size_t)tg * 8] = p;
}

// ---------------- MFMA GEMM body ----------------
// Block = 4 waves; wave = 16 rows x ALL N cols; C/D layout verified (m89/m91).
template<int N, bool AF32, bool USELDS>
__device__ __forceinline__ void gemm_body(int gb, int t,
        const float* __restrict__ Xf, const unsigned short* __restrict__ Xb,
        const unsigned short* __restrict__ Wlg,
        const float* __restrict__ asrc, const float* __restrict__ adst,
        unsigned short* __restrict__ Hb, float* __restrict__ als,
        float* __restrict__ ald, int M, unsigned short* Wl) {
    constexpr int NF = N / 16;
    const unsigned short* Wsrc;
    if constexpr (USELDS) {
        for (int i = t; i < N * 16; i += 256)
            ((uint4*)Wl)[i] = ((const uint4*)Wlg)[i];
        __syncthreads();
        Wsrc = Wl;
    } else {
        Wsrc = Wlg;
    }

    const int lane = t & 63, w = t >> 6;
    const int rb = gb * 64 + w * 16;
    const int cl = lane & 15, g = lane >> 4;

    f32x4 acc[NF];
    #pragma unroll
    for (int n = 0; n < NF; ++n) acc[n] = (f32x4){0.f, 0.f, 0.f, 0.f};

    const float* Xrow = nullptr;
    const unsigned short* Abase = nullptr;
    if constexpr (AF32) {
        const int arow = (rb + cl < M) ? (rb + cl) : (M - 1);
        Xrow = Xf + (size_t)arow * 128;
    } else {
        Abase = Xb + (size_t)(rb >> 4) * 2048 + cl * 8;
    }

    #pragma unroll
    for (int s = 0; s < 4; ++s) {
        bf16x8 af;
        if constexpr (AF32) {
            const int k0 = (s * 4 + g) * 8;
            float4 a = *(const float4*)&Xrow[k0];
            float4 c = *(const float4*)&Xrow[k0 + 4];
            uint4v uu;
            uu[0] = pack2(a.x, a.y); uu[1] = pack2(a.z, a.w);
            uu[2] = pack2(c.x, c.y); uu[3] = pack2(c.z, c.w);
            af = __builtin_bit_cast(bf16x8, uu);
        } else {
            af = *(const bf16x8*)(Abase + (s * 4 + g) * 128);
        }
        #pragma unroll
        for (int n = 0; n < NF; ++n) {
            bf16x8 bfv = *(const bf16x8*)(Wsrc + ((s * 4 + g) * N + n * 16 + cl) * 8);
            acc[n] = __builtin_amdgcn_mfma_f32_16x16x32_bf16(af, bfv, acc[n], 0, 0, 0);
        }
    }

    float asv[NF], adv[NF];
    #pragma unroll
    for (int n = 0; n < NF; ++n) {
        asv[n] = asrc[n * 16 + cl];
        adv[n] = adst[n * 16 + cl];
    }

    #pragma unroll
    for (int r = 0; r < 4; ++r) {
        float ps = 0.f, pd = 0.f;
        #pragma unroll
        for (int n = 0; n < NF; ++n) {
            ps += acc[n][r] * asv[n];
            pd += acc[n][r] * adv[n];
        }
        #pragma unroll
        for (int mask = 1; mask < 16; mask <<= 1) {
            ps += __shfl_xor(ps, mask);
            pd += __shfl_xor(pd, mask);
        }
        const int row = rb + g * 4 + r;
        if (cl == 0 && row < M) { als[row] = ps; ald[row] = pd; }
    }

    #pragma unroll
    for (int r = 0; r < 4; ++r) {
        const int row = rb + g * 4 + r;
        if (row >= M) continue;
        #pragma unroll
        for (int n = 0; n < NF; ++n)
            Hb[(size_t)(n >> 1) * (size_t)M * 32 + (size_t)row * 32
               + (n & 1) * 16 + cl] = (unsigned short)bf16_rne(acc[n][r]);
    }
}

// ---------------- D2: [LDS-histogram count || gemm1] ----------------
__global__ __launch_bounds__(256) void k_par1(
        const int* __restrict__ ei, unsigned* __restrict__ cnt_s,
        unsigned char* __restrict__ rank8,
        const float* __restrict__ X, const unsigned short* __restrict__ Wl1,
        const float* __restrict__ asrc, const float* __restrict__ adst,
        unsigned short* __restrict__ Hb, float* __restrict__ als,
        float* __restrict__ ald, int M) {
    __shared__ unsigned lcnt[NDW];               // 50 KB
    const int b = blockIdx.x, t = threadIdx.x;
    if (b < NSH) {
        const int s = b;
        for (int i = t; i < NDW; i += 256) lcnt[i] = 0;
        __syncthreads();
        const int base = s * EPS;
        const int* __restrict__ dst = ei + N_EDGES;
        for (int j = base + t; j < base + EPS; j += 256) {
            int d = __builtin_nontemporal_load(&dst[j]);
            unsigned sh = 8u * (d & 3);
            unsigned old = atomicAdd(&lcnt[d >> 2], 1u << sh);
            rank8[j] = (unsigned char)((old >> sh) & 0xFFu);
        }
        __syncthreads();
        unsigned* __restrict__ outp = cnt_s + (size_t)s * NDW;
        for (int i = t; i < NDW; i += 256) outp[i] = lcnt[i];
        return;
    }
    gemm_body<HID, true, false>(b - NSH, t, X, nullptr, Wl1,
                                asrc, adst, Hb, als, ald, M, nullptr);
}

// ---------------- scan1: fold shard counts -> degree, u8 bases, padded scan ----
__global__ void k_scan1(const unsigned* __restrict__ cnt_s, int* __restrict__ cntT,
                        unsigned char* __restrict__ pcoff8,
                        int* __restrict__ off, int* __restrict__ bsum, int n) {
    __shared__ int s[256];
    int t = threadIdx.x;
    int i = blockIdx.x * 256 + t;
    int padded = 0;
    if (i < n) {
        const int dw = i >> 2;
        const unsigned sh = 8u * (i & 3);
        int pc = 1;                        // slot 0 = self-loop
        for (int c = 0; c < NSH; ++c) {
            pcoff8[(size_t)c * n + i] = (unsigned char)pc;
            pc += (int)((cnt_s[(size_t)c * NDW + dw] >> sh) & 0xFFu);
        }
        cntT[i] = pc;                      // true degree (incl. self-loop)
        padded = (pc + 3) & ~3;            // pad segments to 4
    }
    s[t] = padded;
    __syncthreads();
    for (int d = 1; d < 256; d <<= 1) {
        int x = (t >= d) ? s[t - d] : 0;
        __syncthreads();
        s[t] += x;
        __syncthreads();
    }
    if (i < n) off[i + 1] = s[t];
    if (t == 255) bsum[blockIdx.x] = s[255];
}

// scan3 (scan2 folded in): every block redundantly scans bsum, applies prefix.
__global__ void k_scan3(int* __restrict__ off, const int* __restrict__ bsum, int n) {
    __shared__ int s[256];
    int t = threadIdx.x;
    s[t] = (t < NBN) ? bsum[t] : 0;
    __syncthreads();
    for (int d = 1; d < 256; d <<= 1) {
        int x = (t >= d) ? s[t - d] : 0;
        __syncthreads();
        s[t] += x;
        __syncthreads();
    }
    int base = (blockIdx.x > 0) ? s[blockIdx.x - 1] : 0;   // blockIdx < 196 < 256
    int i = blockIdx.x * 256 + t;
    if (i < n) off[i + 1] += base;
    if (i == 0) off[0] = 0;
}

// ---------------- fill WITH fused layer-1 edge weights (no csr) ----------------
// Pads never written; SpMM masks slots >= cnt (garbage src < 65536 keeps
// gathers inside the workspace; contributions forced to 0 via select).
__global__ void k_fillw(const int* __restrict__ ei, const int* __restrict__ off,
                        const unsigned char* __restrict__ rank8,
                        const unsigned char* __restrict__ pcoff8,
                        const float* __restrict__ als, const float* __restrict__ ald,
                        unsigned* __restrict__ ew, int e, int n) {
    int i = blockIdx.x * 256 + threadIdx.x;
    if (i < e) {
        int src = __builtin_nontemporal_load(&ei[i]);
        int dst = __builtin_nontemporal_load(&ei[e + i]);
        int c = i / EPS;
        int pos = off[dst] + (int)pcoff8[(size_t)c * n + dst] + (int)rank8[i];
        float ev = als[src] + ald[dst];
        ev = ev > 0.f ? ev : 0.2f * ev;
        ew[pos] = ((unsigned)src << 16) | bf16_rne(__expf(ev));
    } else if (i < e + n) {
        int v = i - e;
        float ev = als[v] + ald[v];
        ev = ev > 0.f ? ev : 0.2f * ev;
        ew[off[v]] = ((unsigned)v << 16) | bf16_rne(__expf(ev));   // self-loop slot 0
    }
}

// ---------------- layer-2 GEMM (A from Xb2-tiled bf16; LDS W) ----------------
__global__ __launch_bounds__(256) void gemm_mfma64(
        const unsigned short* __restrict__ Xb, const unsigned short* __restrict__ Wlg,
        const float* __restrict__ asrc, const float* __restrict__ adst,
        unsigned short* __restrict__ Hb, float* __restrict__ als,
        float* __restrict__ ald, int M) {
    __shared__ unsigned short Wl[16 * 64 * 8];    // 16 KB
    gemm_body<OUT_CH, false, true>(blockIdx.x, threadIdx.x, nullptr, Xb, Wlg,
                                   asrc, adst, Hb, als, ald, M, Wl);
}

// ---------------- unified SpMM with inline softmax denominator ----------------
// Wave = 16 nodes; 4-lane sub owns one node; lane = 8 bf16 feats. Each lane
// accumulates the full denominator locally (broadcast quads); pads masked via
// slot < rend. INLINEW (layer 2): w recomputed from ew's src field.
template<int F, bool RELU, bool PACKOUT, bool INLINEW>
__global__ __launch_bounds__(256) void k_spmm_b(
        const unsigned short* __restrict__ Hb, const unsigned* __restrict__ ew,
        const float* __restrict__ als, const float* __restrict__ ald,
        const float* __restrict__ bias, const int* __restrict__ off,
        const int* __restrict__ cntT, void* __restrict__ outv, int n) {
    constexpr int NCH = F / 32;
    const int chunk = blockIdx.x % NCH;
    const int v = (blockIdx.x / NCH) * 64 + (threadIdx.x >> 2);
    if (v >= n) return;
    const int q = threadIdx.x & 3;                // 8-feat group 0..3
    const int start = off[v], pend = off[v + 1];  // padded: multiple of 4, >= 4
    const int rend = start + cntT[v];             // real end (mask bound)
    const float aldv = INLINEW ? ald[v] : 0.f;
    const unsigned short* __restrict__ Hch = Hb + (size_t)chunk * (size_t)n * 32 + q * 8;

    float a0[8] = {}, a1[8] = {}, a2[8] = {}, a3[8] = {};
    float denom = 0.f;

    #define GATB(E, A, IDX)                                              \
        {                                                                \
            float w_;                                                    \
            if (INLINEW) {                                               \
                int s_ = (int)((E) >> 16);                               \
                float e_ = als[s_] + aldv;                               \
                e_ = e_ > 0.f ? e_ : 0.2f * e_;                          \
                w_ = __expf(e_);                                         \
            } else {                                                     \
                w_ = __uint_as_float((E) << 16);                         \
            }                                                            \
            w_ = ((IDX) < rend) ? w_ : 0.f;                              \
            denom += w_;                                                 \
            uint4 h_ = *(const uint4*)&Hch[(size_t)((E) >> 16) * 32];    \
            A[0] += w_ * __uint_as_float(h_.x << 16);                    \
            A[1] += w_ * __uint_as_float(h_.x & 0xffff0000u);            \
            A[2] += w_ * __uint_as_float(h_.y << 16);                    \
            A[3] += w_ * __uint_as_float(h_.y & 0xffff0000u);            \
            A[4] += w_ * __uint_as_float(h_.z << 16);                    \
            A[5] += w_ * __uint_as_float(h_.z & 0xffff0000u);            \
            A[6] += w_ * __uint_as_float(h_.w << 16);                    \
            A[7] += w_ * __uint_as_float(h_.w & 0xffff0000u);            \
        }
    #define GATB4(Q, J) GATB((Q).x, a0, (J)) GATB((Q).y, a1, (J)+1) \
                        GATB((Q).z, a2, (J)+2) GATB((Q).w, a3, (J)+3)

    int j = start;
    for (; j + 4 < pend; j += 8) {
        uint4 eA = *(const uint4*)&ew[j];
        uint4 eB = *(const uint4*)&ew[j + 4];
        GATB4(eA, j)
        GATB4(eB, j + 4)
    }
    if (j < pend) {
        uint4 eA = *(const uint4*)&ew[j];
        GATB4(eA, j)
    }
    #undef GATB4
    #undef GATB

    const float inv = 1.f / (denom + 1e-16f);
    const float* __restrict__ bp = bias + chunk * 32 + q * 8;
    float s[8];
    #pragma unroll
    for (int i = 0; i < 8; ++i) {
        s[i] = (a0[i] + a1[i] + a2[i] + a3[i]) * inv + bp[i];
        if (RELU) s[i] = fmaxf(s[i], 0.f);
    }

    if (PACKOUT) {
        unsigned short* Xb2 = (unsigned short*)outv;
        const int kg = chunk * 4 + q;
        uint4v p;
        p[0] = pack2(s[0], s[1]); p[1] = pack2(s[2], s[3]);
        p[2] = pack2(s[4], s[5]); p[3] = pack2(s[6], s[7]);
        __builtin_nontemporal_store(p,
            (uint4v*)&Xb2[(size_t)(v >> 4) * 2048 + kg * 128 + (v & 15) * 8]);
    } else {
        float* out = (float*)outv;
        float4v o0, o1;
        o0[0] = s[0]; o0[1] = s[1]; o0[2] = s[2]; o0[3] = s[3];
        o1[0] = s[4]; o1[1] = s[5]; o1[2] = s[6]; o1[3] = s[7];
        float* op = out + (size_t)v * F + chunk * 32 + q * 8;
        __builtin_nontemporal_store(o0, (float4v*)op);
        __builtin_nontemporal_store(o1, (float4v*)(op + 4));
    }
}

// ---------------- launch ----------------

extern "C" void kernel_launch(void* const* d_in, const int* in_sizes, int n_in,
                              void* d_out, int out_size, void* d_ws, size_t ws_size,
                              hipStream_t stream) {
    const float* x     = (const float*)d_in[0];
    const int*   ei    = (const int*)d_in[1];
    const float* W1    = (const float*)d_in[2];
    const float* as1   = (const float*)d_in[3];
    const float* ad1   = (const float*)d_in[4];
    const float* b1    = (const float*)d_in[5];
    const float* W2    = (const float*)d_in[6];
    const float* as2   = (const float*)d_in[7];
    const float* ad2   = (const float*)d_in[8];
    const float* b2    = (const float*)d_in[9];
    float* out = (float*)d_out;

    const int Nn = N_NODES;

    // workspace carve-up (256B aligned)
    char* ws = (char*)d_ws;
    size_t o = 0;
    auto carve = [&](size_t bytes) { char* p = ws + o; o = (o + bytes + 255) & ~(size_t)255; return p; };
    int*            off   = (int*)carve((Nn + 1) * sizeof(int));
    int*            cntT  = (int*)carve(Nn * sizeof(int));
    int*            bsum  = (int*)carve(256 * sizeof(int));
    unsigned char*  rank8 = (unsigned char*)carve((size_t)N_EDGES);
    unsigned*       cnt_s = (unsigned*)carve((size_t)NSH * NDW * sizeof(unsigned));
    unsigned char*  pcoff8= (unsigned char*)carve((size_t)NSH * Nn);
    unsigned*       ew    = (unsigned*)carve((size_t)ET_PAD * sizeof(unsigned));
    unsigned short* h1b   = (unsigned short*)carve((size_t)Nn * HID * sizeof(unsigned short));
    unsigned short* h2b   = (unsigned short*)carve((size_t)Nn * OUT_CH * sizeof(unsigned short));
    unsigned short* Xb2   = (unsigned short*)carve((size_t)MPAD * 128 * sizeof(unsigned short));
    unsigned short* Wl1   = (unsigned short*)carve(16 * 128 * 8 * sizeof(unsigned short));
    unsigned short* Wl2   = (unsigned short*)carve(16 * 64 * 8 * sizeof(unsigned short));
    float*          als1v = (float*)carve(Nn * sizeof(float));
    float*          ald1v = (float*)carve(Nn * sizeof(float));
    float*          als2v = (float*)carve(Nn * sizeof(float));
    float*          ald2v = (float*)carve(Nn * sizeof(float));

    // D1: W converts
    k_pre<<<12, 256, 0, stream>>>(W1, Wl1, W2, Wl2);

    // D2: [LDS-hist count || gemm1(f32-X inline, global-W)]
    k_par1<<<NSH + NB_GEMM, 256, 0, stream>>>(
        ei, cnt_s, rank8, x, Wl1, as1, ad1, h1b, als1v, ald1v, Nn);

    // D3-4: scans
    k_scan1<<<NBN, 256, 0, stream>>>(cnt_s, cntT, pcoff8, off, bsum, Nn);
    k_scan3<<<NBN, 256, 0, stream>>>(off, bsum, Nn);

    // D5: fill + fused layer-1 edge weights
    k_fillw<<<NB_ET, 256, 0, stream>>>(ei, off, rank8, pcoff8, als1v, ald1v,
                                       ew, N_EDGES, Nn);

    const int nbN64 = (Nn + 63) / 64;

    // D6: layer-1 SpMM (inline denom; y1 written in Xb-tiled bf16 layout)
    k_spmm_b<HID, true, true, false><<<nbN64 * (HID / 32), 256, 0, stream>>>(
        h1b, ew, nullptr, nullptr, b1, off, cntT, Xb2, Nn);

    // D7: layer-2 GEMM
    gemm_mfma64<<<NB_GEMM, 256, 0, stream>>>(
        Xb2, Wl2, as2, ad2, h2b, als2v, ald2v, Nn);

    // D8: layer-2 SpMM (inline w from src field + inline denom)
    k_spmm_b<OUT_CH, false, false, true><<<nbN64 * (OUT_CH / 32), 256, 0, stream>>>(
        h2b, ew, als2v, ald2v, b2, off, cntT, out, Nn);
}